// Round 12
// baseline (195.810 us; speedup 1.0000x reference)
//
#include <hip/hip_runtime.h>
#include <hip/hip_bf16.h>

#define HID 4096
#define EQKV 6144
#define NH 32
#define NKV 8
#define GQ 4
#define D 128
#define WIN 2048
#define NCH 32   // K-chunks for split-K GEMM (4096 / 128)
#define CHH 128  // h per chunk
#define NCHK 8   // position chunks for attention
#define CLEN (WIN / NCHK)   // 256

// ------- split-K GEMM: part[chunk][b][e] = sum_{h in chunk} X[b][h] * W[h][e]
template<int E>
__global__ __launch_bounds__(256) void k_gemm_split(const float* __restrict__ X,
                                                    const float* __restrict__ W,
                                                    float* __restrict__ part) {
    __shared__ float xs[CHH][36];
    const int t = threadIdx.x;
    const int wv = t >> 6, ln = t & 63;
    const int e0 = blockIdx.x * 256 + ln * 4;
    const int h0 = blockIdx.y * CHH;
    const int bs0 = wv * 8;

    {   // stage X[0..32)[h0..h0+128) -> xs[hl][b]
        const int b = t >> 3, seg = t & 7;
        const float* xp = X + (size_t)b * HID + h0 + seg * 16;
#pragma unroll
        for (int i = 0; i < 4; ++i) {
            const float4 v = *(const float4*)(xp + i * 4);
            xs[seg * 16 + i * 4 + 0][b] = v.x;
            xs[seg * 16 + i * 4 + 1][b] = v.y;
            xs[seg * 16 + i * 4 + 2][b] = v.z;
            xs[seg * 16 + i * 4 + 3][b] = v.w;
        }
    }
    __syncthreads();

    float4 acc[8];
#pragma unroll
    for (int i = 0; i < 8; ++i) acc[i] = make_float4(0.f, 0.f, 0.f, 0.f);

    const float* Wp = W + (size_t)h0 * E + e0;
    float4 wb[4];
#pragma unroll
    for (int i = 0; i < 4; ++i) wb[i] = *(const float4*)(Wp + (size_t)i * E);
    Wp += (size_t)4 * E;

    for (int h = 0; h < CHH; h += 4) {
        float4 wc[4];
#pragma unroll
        for (int i = 0; i < 4; ++i) wc[i] = wb[i];
        if (h + 4 < CHH) {
#pragma unroll
            for (int i = 0; i < 4; ++i) wb[i] = *(const float4*)(Wp + (size_t)i * E);
            Wp += (size_t)4 * E;
        }
#pragma unroll
        for (int i = 0; i < 4; ++i) {
            const float4 w4 = wc[i];
            const float4 xa = *(const float4*)&xs[h + i][bs0];
            const float4 xb = *(const float4*)&xs[h + i][bs0 + 4];
            const float xr[8] = {xa.x, xa.y, xa.z, xa.w, xb.x, xb.y, xb.z, xb.w};
#pragma unroll
            for (int bb = 0; bb < 8; ++bb) {
                acc[bb].x = fmaf(xr[bb], w4.x, acc[bb].x);
                acc[bb].y = fmaf(xr[bb], w4.y, acc[bb].y);
                acc[bb].z = fmaf(xr[bb], w4.z, acc[bb].z);
                acc[bb].w = fmaf(xr[bb], w4.w, acc[bb].w);
            }
        }
    }

#pragma unroll
    for (int bb = 0; bb < 8; ++bb)
        *(float4*)(part + ((size_t)blockIdx.y * 32 + bs0 + bb) * E + e0) = acc[bb];
}

// ---------------- final reduce of wo-GEMM partials -> d_out ----------------
__global__ void k_reduce_f32(const float* __restrict__ part,
                             float* __restrict__ out, const int n) {
    const int i4 = (blockIdx.x * 256 + threadIdx.x) * 4;
    if (i4 >= n) return;
    float4 s = make_float4(0.f, 0.f, 0.f, 0.f);
#pragma unroll
    for (int c = 0; c < NCH; ++c) {
        const float4 p = *(const float4*)(part + (size_t)c * n + i4);
        s.x += p.x; s.y += p.y; s.z += p.z; s.w += p.w;
    }
    *(float4*)(out + i4) = s;
}

// ------- fused: reduce qkv partials + rope (q,k) + v extract -------
__global__ __launch_bounds__(128) void k_finish(
        const float* __restrict__ part, const float* __restrict__ R,
        float* __restrict__ q_rot, float* __restrict__ k_rot,
        float* __restrict__ v_new) {
    __shared__ float sq[D];
    const int bid = blockIdx.x;
    const int b = bid / 48, u = bid % 48;
    const int tid = threadIdx.x;
    const int e0 = u * D;

    float s = 0.f;
#pragma unroll
    for (int c = 0; c < NCH; ++c)
        s += part[((size_t)c * 32 + b) * EQKV + e0 + tid];

    if (u < 40) {   // q or k: rope
        sq[tid] = s;
        __syncthreads();
        float acc = 0.f;
        for (int d = 0; d < D; d += 4) {
            const float r0 = R[(size_t)(d + 0) * D + tid];
            const float r1 = R[(size_t)(d + 1) * D + tid];
            const float r2 = R[(size_t)(d + 2) * D + tid];
            const float r3 = R[(size_t)(d + 3) * D + tid];
            acc = fmaf(sq[d + 0], r0, acc);
            acc = fmaf(sq[d + 1], r1, acc);
            acc = fmaf(sq[d + 2], r2, acc);
            acc = fmaf(sq[d + 3], r3, acc);
        }
        if (u < 32) q_rot[((size_t)b * NH + u) * D + tid] = acc;
        else        k_rot[((size_t)b * NKV + (u - 32)) * D + tid] = acc;
    } else {        // v: plain reduce
        v_new[((size_t)b * NKV + (u - 40)) * D + tid] = s;
    }
}

// ------- QK^T pure stream: one block per (b, kv, chunk) -------
// Writes S_glob[bkv][p][g] = exp(score) (float4/row) + per-chunk exp-sums.
__global__ __launch_bounds__(256) void k_qkt(
        const float* __restrict__ q_rot, const float* __restrict__ k_rot,
        const float* __restrict__ cache_k,
        const int* __restrict__ p_start, const int* __restrict__ p_cur,
        float* __restrict__ S_glob, float* __restrict__ psum) {
    __shared__ float qs[4 * D];
    __shared__ float kn[D];
    __shared__ float sred[4][4];
    __shared__ float patch[4];

    const int t = threadIdx.x;
    const int bid = blockIdx.x;
    const int bkv = bid >> 3, c = bid & (NCHK - 1);
    const int b = bkv >> 3, kv = bkv & 7;
    const int l = t & 63, w = t >> 6;
    const int ls = min(p_start[0] + 1, WIN);
    const int cur = p_cur[0];
    const int p0 = c * CLEN;
    const int pend = min(ls, p0 + CLEN);
    const int cnt = pend - p0;
    const bool full = (cnt == CLEN);

    const float scale = 0.08838834764831845f;   // 1/sqrt(128)
    {   // stage scaled q + new k
        const float* qsrc = q_rot + ((size_t)b * NH + kv * GQ) * D;
        qs[t] = qsrc[t] * scale;
        qs[t + 256] = qsrc[t + 256] * scale;
        if (t < 128) kn[t] = k_rot[((size_t)b * NKV + kv) * D + t];
    }
    __syncthreads();

    const size_t base = (size_t)bkv * WIN * D;
    const int sub = l & 15, r = l >> 4;     // 16 lanes/row, 4 rows/iter/wave
    const int d0 = sub * 8;

    float qreg[4][8];
#pragma unroll
    for (int g = 0; g < 4; ++g)
#pragma unroll
        for (int j = 0; j < 8; ++j) qreg[g][j] = qs[g * D + d0 + j];

    float esum[4] = {0.f, 0.f, 0.f, 0.f};

    if (full) {
        const float* kp = cache_k + base + (size_t)(p0 + w * 64 + r) * D + d0;
        float4 A = *(const float4*)kp;
        float4 C = *(const float4*)(kp + 4);
        int pl = w * 64 + r;
        for (int it = 0; it < 16; ++it) {
            const float4 a = A, cc = C;
            kp += (size_t)4 * D;
            if (it + 1 < 16) {
                A = *(const float4*)kp;
                C = *(const float4*)(kp + 4);
            }
            const float kk[8] = {a.x, a.y, a.z, a.w, cc.x, cc.y, cc.z, cc.w};
            float s4[4] = {0.f, 0.f, 0.f, 0.f};
#pragma unroll
            for (int g = 0; g < 4; ++g)
#pragma unroll
                for (int j = 0; j < 8; ++j) s4[g] = fmaf(qreg[g][j], kk[j], s4[g]);
#pragma unroll
            for (int off = 1; off < 16; off <<= 1)
#pragma unroll
                for (int g = 0; g < 4; ++g) s4[g] += __shfl_xor(s4[g], off, 16);
            if (sub == 0) {
                float4 e4;
                e4.x = __expf(s4[0]); e4.y = __expf(s4[1]);
                e4.z = __expf(s4[2]); e4.w = __expf(s4[3]);
                esum[0] += e4.x; esum[1] += e4.y; esum[2] += e4.z; esum[3] += e4.w;
                *(float4*)(S_glob + ((size_t)bkv * WIN + p0 + pl) * 4) = e4;
            }
            pl += 4;
        }
    } else {
        for (int it = 0; it < 16; ++it) {
            const int p = p0 + w * 64 + it * 4 + r;
            if (p < pend) {
                const float* kp = cache_k + base + (size_t)p * D + d0;
                const float4 a = *(const float4*)kp;
                const float4 cc = *(const float4*)(kp + 4);
                const float kk[8] = {a.x, a.y, a.z, a.w, cc.x, cc.y, cc.z, cc.w};
                float s4[4] = {0.f, 0.f, 0.f, 0.f};
#pragma unroll
                for (int g = 0; g < 4; ++g)
#pragma unroll
                    for (int j = 0; j < 8; ++j) s4[g] = fmaf(qreg[g][j], kk[j], s4[g]);
#pragma unroll
                for (int off = 1; off < 16; off <<= 1)
#pragma unroll
                    for (int g = 0; g < 4; ++g) s4[g] += __shfl_xor(s4[g], off, 16);
                if (sub == 0) {
                    float4 e4;
                    e4.x = __expf(s4[0]); e4.y = __expf(s4[1]);
                    e4.z = __expf(s4[2]); e4.w = __expf(s4[3]);
                    esum[0] += e4.x; esum[1] += e4.y; esum[2] += e4.z; esum[3] += e4.w;
                    *(float4*)(S_glob + ((size_t)bkv * WIN + p) * 4) = e4;
                }
            }
        }
    }

    // wave reduce esum (non-contributing lanes hold 0)
#pragma unroll
    for (int off = 16; off <= 32; off <<= 1)
#pragma unroll
        for (int g = 0; g < 4; ++g) esum[g] += __shfl_xor(esum[g], off, 64);
    if (l == 0) {
#pragma unroll
        for (int g = 0; g < 4; ++g) sred[w][g] = esum[g];
    }
    __syncthreads();   // also makes this block's S_glob stores visible

    // patch position cur with the NEW k; record delta for psum
    if (t < 4) {
        float delta = 0.f;
        if (cur >= p0 && cur < pend) {
            const float e_old = S_glob[((size_t)bkv * WIN + cur) * 4 + t];
            float a = 0.f;
            for (int d = 0; d < D; ++d) a = fmaf(qs[t * D + d], kn[d], a);
            const float e_new = __expf(a);
            S_glob[((size_t)bkv * WIN + cur) * 4 + t] = e_new;
            delta = e_new - e_old;
        }
        patch[t] = delta;
    }
    __syncthreads();

    if (t < 4)
        psum[((size_t)bkv * 4 + t) * NCHK + c] =
            sred[0][t] + sred[1][t] + sred[2][t] + sred[3][t] + patch[t];
}

// ------- PV pure stream: one block per (b, kv, chunk) -------
__global__ __launch_bounds__(256) void k_pv(
        const float* __restrict__ v_new, const float* __restrict__ cache_v,
        const float* __restrict__ S_glob, const float* __restrict__ psum,
        const int* __restrict__ p_start, const int* __restrict__ p_cur,
        float* __restrict__ pacc) {
    __shared__ float sl[CLEN * 4];      // S chunk (exp values), 4 KB
    __shared__ float vn[D];
    __shared__ float rcp[4];
    __shared__ float red[4 * 4 * D];

    const int t = threadIdx.x;
    const int bid = blockIdx.x;
    const int bkv = bid >> 3, c = bid & (NCHK - 1);
    const int b = bkv >> 3, kv = bkv & 7;
    const int l = t & 63, w = t >> 6;
    const int ls = min(p_start[0] + 1, WIN);
    const int cur = p_cur[0];
    const int p0 = c * CLEN;
    const int pend = min(ls, p0 + CLEN);
    const int cnt = pend - p0;
    const bool full = (cnt == CLEN);

    {   // stage S chunk, vn, recips
        ((float4*)sl)[t] = ((const float4*)(S_glob + (size_t)(bkv * WIN + p0) * 4))[t];
        if (t < 128) vn[t] = v_new[((size_t)b * NKV + kv) * D + t];
        if (t >= 128 && t < 132) {
            const int g = t - 128;
            float tot = 0.f;
#pragma unroll
            for (int cc2 = 0; cc2 < NCHK; ++cc2)
                tot += psum[((size_t)bkv * 4 + g) * NCHK + cc2];
            rcp[g] = 1.f / tot;
        }
    }
    __syncthreads();

    const size_t base = (size_t)bkv * WIN * D;
    const int s = l & 15, r2 = l >> 4;      // 16 lanes/row, 4 rows/iter/wave
    const int d0 = s * 8;

    float acc[4][8];
#pragma unroll
    for (int g = 0; g < 4; ++g)
#pragma unroll
        for (int j = 0; j < 8; ++j) acc[g][j] = 0.f;

    if (full) {
        const float* vp = cache_v + base + (size_t)(p0 + w * 64 + r2) * D + d0;
        float4 A = *(const float4*)vp;
        float4 C = *(const float4*)(vp + 4);
        int pl = w * 64 + r2;
        for (int it = 0; it < 16; ++it) {
            const float4 a = A, cc = C;
            vp += (size_t)4 * D;
            if (it + 1 < 16) {
                A = *(const float4*)vp;
                C = *(const float4*)(vp + 4);
            }
            const float vv[8] = {a.x, a.y, a.z, a.w, cc.x, cc.y, cc.z, cc.w};
            const float4 e4 = ((const float4*)sl)[pl];
#pragma unroll
            for (int j = 0; j < 8; ++j) {
                acc[0][j] = fmaf(e4.x, vv[j], acc[0][j]);
                acc[1][j] = fmaf(e4.y, vv[j], acc[1][j]);
                acc[2][j] = fmaf(e4.z, vv[j], acc[2][j]);
                acc[3][j] = fmaf(e4.w, vv[j], acc[3][j]);
            }
            pl += 4;
        }
        // post-hoc fix of position cur: acc += e[cur]*(vn - v_cached)
        if (cur >= p0 && cur < pend) {
            const int lr = cur - p0;
            if (w == (lr >> 6) && r2 == (lr & 3)) {
                const float* vc = cache_v + base + (size_t)cur * D + d0;
                const float4 a = *(const float4*)vc;
                const float4 cc = *(const float4*)(vc + 4);
                const float vv[8] = {a.x, a.y, a.z, a.w, cc.x, cc.y, cc.z, cc.w};
                const float4 e4 = ((const float4*)sl)[lr];
#pragma unroll
                for (int j = 0; j < 8; ++j) {
                    const float dv = vn[d0 + j] - vv[j];
                    acc[0][j] = fmaf(e4.x, dv, acc[0][j]);
                    acc[1][j] = fmaf(e4.y, dv, acc[1][j]);
                    acc[2][j] = fmaf(e4.z, dv, acc[2][j]);
                    acc[3][j] = fmaf(e4.w, dv, acc[3][j]);
                }
            }
        }
    } else {
        float vn8[8];
#pragma unroll
        for (int j = 0; j < 8; ++j) vn8[j] = vn[d0 + j];
        for (int it = 0; it < 16; ++it) {
            const int p = p0 + w * 64 + it * 4 + r2;
            if (p < pend) {
                const float4 a = *(const float4*)(cache_v + base + (size_t)p * D + d0);
                const float4 cc = *(const float4*)(cache_v + base + (size_t)p * D + d0 + 4);
                float vv[8] = {a.x, a.y, a.z, a.w, cc.x, cc.y, cc.z, cc.w};
                if (p == cur) {
#pragma unroll
                    for (int j = 0; j < 8; ++j) vv[j] = vn8[j];
                }
                const float4 e4 = ((const float4*)sl)[p - p0];
#pragma unroll
                for (int j = 0; j < 8; ++j) {
                    acc[0][j] = fmaf(e4.x, vv[j], acc[0][j]);
                    acc[1][j] = fmaf(e4.y, vv[j], acc[1][j]);
                    acc[2][j] = fmaf(e4.z, vv[j], acc[2][j]);
                    acc[3][j] = fmaf(e4.w, vv[j], acc[3][j]);
                }
            }
        }
    }

    // in-wave reduce over the 4 row-groups (lane bits 4,5)
#pragma unroll
    for (int off = 16; off <= 32; off <<= 1)
#pragma unroll
        for (int g = 0; g < 4; ++g)
#pragma unroll
            for (int j = 0; j < 8; ++j)
                acc[g][j] += __shfl_xor(acc[g][j], off, 64);
    if (l < 16) {
#pragma unroll
        for (int g = 0; g < 4; ++g)
#pragma unroll
            for (int j = 0; j < 8; ++j)
                red[(w * 4 + g) * D + l * 8 + j] = acc[g][j];
    }
    __syncthreads();

    {   // cross-wave reduce + normalize + write partials
        const int d = t & 127, half = t >> 7;
#pragma unroll
        for (int gi = 0; gi < 2; ++gi) {
            const int g = half + gi * 2;
            float sum = 0.f;
#pragma unroll
            for (int w4 = 0; w4 < 4; ++w4) sum += red[(w4 * 4 + g) * D + d];
            const int hidx = bkv * GQ + g;
            pacc[((size_t)hidx * NCHK + c) * D + d] = sum * rcp[g];
        }
    }
}

// ------- combine: plain sum of normalized partials -------
__global__ __launch_bounds__(512) void k_attn_combine(
        const float* __restrict__ pacc, float* __restrict__ attn_out) {
    const int t = threadIdx.x;
    const int bkv = blockIdx.x;
    const int b = bkv >> 3, kv = bkv & 7;
    const int g = t >> 7, d = t & 127;
    const int hidx = bkv * GQ + g;

    float acc = 0.f;
#pragma unroll
    for (int c = 0; c < NCHK; ++c)
        acc += pacc[((size_t)hidx * NCHK + c) * D + d];
    attn_out[(size_t)b * HID + (kv * GQ + g) * D + d] = acc;
}

// ---------------- host launch ----------------
extern "C" void kernel_launch(void* const* d_in, const int* in_sizes, int n_in,
                              void* d_out, int out_size, void* d_ws, size_t ws_size,
                              hipStream_t stream) {
    const float* x    = (const float*)d_in[0];
    const float* wqkv = (const float*)d_in[1];
    const float* wo   = (const float*)d_in[2];
    const float* rot  = (const float*)d_in[3];
    const float* ck   = (const float*)d_in[4];
    const float* cv   = (const float*)d_in[5];
    const int*   sp   = (const int*)d_in[6];
    const int*   cp   = (const int*)d_in[7];

    float* ws     = (float*)d_ws;
    float* q_rot  = ws;                     // 131072
    float* k_rot  = ws + 131072;            // 32768
    float* v_new  = ws + 163840;            // 32768
    float* attn_o = ws + 196608;            // 131072
    float* part   = ws + 327680;            // NCH*32*6144 = 6291456
    float* S_glob = ws + 6619136;           // 256*2048*4  = 2097152
    float* psum   = ws + 8716288;           // 256*4*8     = 8192
    float* pacc   = ws + 8724480;           // 1024*8*128  = 1048576

    k_gemm_split<EQKV><<<dim3(EQKV / 256, NCH), 256, 0, stream>>>(x, wqkv, part);
    k_finish<<<32 * 48, 128, 0, stream>>>(part, rot, q_rot, k_rot, v_new);
    k_qkt<<<256 * NCHK, 256, 0, stream>>>(q_rot, k_rot, ck, sp, cp, S_glob, psum);
    k_pv<<<256 * NCHK, 256, 0, stream>>>(v_new, cv, S_glob, psum, sp, cp, pacc);
    k_attn_combine<<<256, 512, 0, stream>>>(pacc, attn_o);
    k_gemm_split<HID><<<dim3(HID / 256, NCH), 256, 0, stream>>>(attn_o, wo, part);
    k_reduce_f32<<<128, 256, 0, stream>>>(part, (float*)d_out, 32 * HID);
}